// Round 8
// baseline (86.536 us; speedup 1.0000x reference)
//
#include <hip/hip_runtime.h>
#include <hip/hip_bf16.h>

#define HH 256
#define WW 256
#define NPIX (HH*WW)
#define NS 512

// SoA param arrays in ws (each NS floats): monic-poly coefficients
//   q(x; y) = A2*x^2 + (A1Y*y + A1C)*x + (A0YY*y^2 + A0Y*y + A0C)
#define A_A2   0
#define A_A1Y  1
#define A_A1C  2
#define A_A0YY 3
#define A_A0Y  4
#define A_A0C  5
#define A_C0   6
#define A_C1   7
#define A_C2   8
#define A_SH   9
#define A_TR   10
#define L2_SLOT  (11*NS)
#define CNT_SLOT (11*NS + 1)

#define TEAMS 8                     // waves per k2 block
#define SPT   (NS/TEAMS)            // 64 strokes per wave, one per lane
#define PPT   4                     // pixels per thread (one row, stride 64)
#define BLK   512                   // 8 waves -> 2/SIMD, VGPR cap 128 (no spill)
#define K2_GRID 256                 // one block per image row

#define L2E 1.4426950408889634f     // log2(e)

#if __has_builtin(__builtin_amdgcn_exp2f)
#define EXP2F(x) __builtin_amdgcn_exp2f(x)
#else
#define EXP2F(x) exp2f(x)
#endif
#if __has_builtin(__builtin_amdgcn_rcpf)
#define RCPF(x) __builtin_amdgcn_rcpf(x)
#else
#define RCPF(x) (1.0f/(x))
#endif

__device__ __forceinline__ float rlane(float v, int l) {
#if __has_builtin(__builtin_amdgcn_readlane)
    return __int_as_float(__builtin_amdgcn_readlane(__float_as_int(v), l));
#else
    return __shfl(v, l, 64);
#endif
}

// ---------------------------------------------------------------------------
// Kernel 1: per-stroke constants, pre-scaled by log2(e) so k2 uses raw exp2:
//   q2(x,y) = (P x + Q y + T1)^2 + (R x + S y + T2)^2   ( = log2(e) * quad )
// emitted as monic-poly SoA coefficients in x with y-polynomials for k2.
// Exact discrete max via per-row analytic argmin of the convex quadratic.
// ---------------------------------------------------------------------------
__global__ __launch_bounds__(256) void k1_prep(
    const float* __restrict__ offset, const float* __restrict__ sigma,
    const float* __restrict__ theta,  const float* __restrict__ color,
    const float* __restrict__ alpha,  float* __restrict__ wsf)
{
    const int n = blockIdx.x;
    const int i = threadIdx.x;          // row index

    const float ox = offset[2*n], oy = offset[2*n+1];
    const float s0 = sigma[2*n],  s1 = sigma[2*n+1];
    const float th = theta[n];

    const float kk = sqrtf(0.5f * L2E);
    const float ra = kk / s0;           // ratio = W/H = 1
    const float rb = kk / s1;

    float s, c;
    __sincosf(th, &s, &c);
    // rot = [[c,-s],[s,-c]]:  u = c(x-ox) - s(y-oy);  v = s(x-ox) - c(y-oy)
    const float P = ra * c,  Q = -ra * s,  T1 = ra * (-c * ox + s * oy);
    const float R = rb * s,  S = -rb * c,  T2 = rb * (-s * ox + c * oy);

    // row-min of q2(x) = (P x + beta)^2 + (R x + delta)^2 (convex in x)
    const float y     = (float)i / (float)HH;
    const float beta  = fmaf(Q, y, T1);
    const float delta = fmaf(S, y, T2);
    const float A     = P * P + R * R;
    const float xstar = -(P * beta + R * delta) / A;
    int j0 = (int)floorf(xstar * (float)WW);
    j0 = max(0, min(WW - 1, j0));
    const int j1 = min(WW - 1, j0 + 1);
    const float x0 = (float)j0 / (float)WW, x1 = (float)j1 / (float)WW;
    const float u0 = fmaf(P, x0, beta),  v0 = fmaf(R, x0, delta);
    const float u1 = fmaf(P, x1, beta),  v1 = fmaf(R, x1, delta);
    float q = fminf(u0*u0 + v0*v0, u1*u1 + v1*v1);

    #pragma unroll
    for (int off = 32; off > 0; off >>= 1)
        q = fminf(q, __shfl_down(q, off));
    __shared__ float wmin[4];
    if ((i & 63) == 0) wmin[i >> 6] = q;
    __syncthreads();

    if (i == 0) {
        const float qmin   = fminf(fminf(wmin[0], wmin[1]), fminf(wmin[2], wmin[3]));
        const float maxpdf = EXP2F(-qmin);
        const float base   = alpha[n] / (maxpdf + 1e-6f);
        wsf[A_A2  *NS + n] = P * P + R * R;
        wsf[A_A1Y *NS + n] = 2.0f * (P * Q + R * S);
        wsf[A_A1C *NS + n] = 2.0f * (P * T1 + R * T2);
        wsf[A_A0YY*NS + n] = Q * Q + S * S;
        wsf[A_A0Y *NS + n] = 2.0f * (Q * T1 + S * T2);
        wsf[A_A0C *NS + n] = T1 * T1 + T2 * T2;
        wsf[A_C0  *NS + n] = base * color[3*n];
        wsf[A_C1  *NS + n] = base * color[3*n+1];
        wsf[A_C2  *NS + n] = base * color[3*n+2];
        wsf[A_SH  *NS + n] = fabsf(1.0f - s0 / s1);   // sharpness term
        wsf[A_TR  *NS + n] = fabsf(alpha[n]);         // transparency term
        if (n == 0) {
            wsf[L2_SLOT] = 0.0f;
            ((int*)wsf)[CNT_SLOT] = 0;
        }
    }
}

// ---------------------------------------------------------------------------
// Kernel 2: 256 blocks (one row each) x 512 threads (8 waves = 2/SIMD, VGPR
// cap 128 so guaranteed no spill). Each wave owns 64 strokes; lane l holds
// stroke (wave*64+l)'s row-folded record {a2,a1,a0,c0,c1,c2} in REGISTERS.
// Inner loop: v_readlane broadcast (6 values) + 4 px x (2 fma poly, exp2,
// 3 fma acc). Zero memory ops in the hot loop. LDS cross-team reduce, fused
// sigmoid epilogue + l2 partial, last block finalizes the scalar loss.
// ---------------------------------------------------------------------------
__global__ __launch_bounds__(512) void k2_paint(
    const float* __restrict__ canvas, const float* __restrict__ target,
    const float* __restrict__ prm,    float* __restrict__ out,
    float* __restrict__ l2acc,        int* __restrict__ cnt)
{
    const int tid  = threadIdx.x;
    const int t    = tid & 63;          // lane
    const int w    = tid >> 6;          // wave id 0..7 (= stroke team)
    const int row  = blockIdx.x;
    const float y  = (float)row * (1.0f / (float)HH);

    // ---- stage: lane t holds stroke (w*64 + t), row terms folded ----
    float ra2, ra1, ra0, rc0, rc1, rc2;
    {
        const int n = w * SPT + t;
        ra2 = prm[A_A2*NS + n];
        ra1 = fmaf(prm[A_A1Y*NS + n], y, prm[A_A1C*NS + n]);
        ra0 = fmaf(fmaf(prm[A_A0YY*NS + n], y, prm[A_A0Y*NS + n]), y,
                   prm[A_A0C*NS + n]);
        rc0 = prm[A_C0*NS + n];
        rc1 = prm[A_C1*NS + n];
        rc2 = prm[A_C2*NS + n];
    }

    float xk[PPT];
    #pragma unroll
    for (int k = 0; k < PPT; ++k) xk[k] = (float)(t + 64*k) * (1.0f / (float)WW);

    float acc[PPT][3] = {};
    #pragma unroll
    for (int n = 0; n < SPT; ++n) {     // full unroll -> immediate-lane readlane
        const float a2 = rlane(ra2, n);
        const float a1 = rlane(ra1, n);
        const float a0 = rlane(ra0, n);
        const float c0 = rlane(rc0, n);
        const float c1 = rlane(rc1, n);
        const float c2 = rlane(rc2, n);
        #pragma unroll
        for (int k = 0; k < PPT; ++k) {
            const float tq = fmaf(a2, xk[k], a1);
            const float q  = fmaf(tq, xk[k], a0);
            const float e  = EXP2F(-q);
            acc[k][0] = fmaf(e, c0, acc[k][0]);
            acc[k][1] = fmaf(e, c1, acc[k][1]);
            acc[k][2] = fmaf(e, c2, acc[k][2]);
        }
    }

    // ---- cross-team reduce in LDS ([team][px][ch], stride-3 = 2-way free) --
    __shared__ float sacc[TEAMS][WW][3];     // 24 KB
    #pragma unroll
    for (int k = 0; k < PPT; ++k) {
        sacc[w][t + 64*k][0] = acc[k][0];
        sacc[w][t + 64*k][1] = acc[k][1];
        sacc[w][t + 64*k][2] = acc[k][2];
    }
    __syncthreads();

    __shared__ float lw[4];
    __shared__ int sdone;
    if (tid < WW) {
        float z0 = 0.0f, z1 = 0.0f, z2 = 0.0f;
        #pragma unroll
        for (int tm = 0; tm < TEAMS; ++tm) {
            z0 += sacc[tm][tid][0];
            z1 += sacc[tm][tid][1];
            z2 += sacc[tm][tid][2];
        }
        const int p = row * WW + tid;
        z0 += canvas[p];
        z1 += canvas[NPIX + p];
        z2 += canvas[2*NPIX + p];
        const float o0 = RCPF(1.0f + EXP2F(-z0 * L2E));
        const float o1 = RCPF(1.0f + EXP2F(-z1 * L2E));
        const float o2 = RCPF(1.0f + EXP2F(-z2 * L2E));
        out[p]          = o0;
        out[NPIX + p]   = o1;
        out[2*NPIX + p] = o2;
        const float d0 = o0 - target[p];
        const float d1 = o1 - target[NPIX + p];
        const float d2 = o2 - target[2*NPIX + p];
        float l2loc = d0*d0 + d1*d1 + d2*d2;
        #pragma unroll
        for (int off = 32; off > 0; off >>= 1)
            l2loc += __shfl_down(l2loc, off);
        if (t == 0) lw[tid >> 6] = l2loc;
    }
    __syncthreads();

    if (tid == 0) {
        atomicAdd(l2acc, lw[0] + lw[1] + lw[2] + lw[3]);
        __threadfence();
        const int old = atomicAdd(cnt, 1);
        sdone = (old == K2_GRID - 1) ? 1 : 0;
    }
    __syncthreads();

    if (sdone) {  // exactly one block, after all l2 adds are visible
        float sh = prm[A_SH*NS + tid];   // 512 threads cover NS=512
        float tr = prm[A_TR*NS + tid];
        #pragma unroll
        for (int off = 32; off > 0; off >>= 1) {
            sh += __shfl_down(sh, off);
            tr += __shfl_down(tr, off);
        }
        if (t == 0) { sacc[0][w][0] = sh; sacc[0][w][1] = tr; }
        __syncthreads();
        if (tid == 0) {
            float shs = 0.0f, trs = 0.0f;
            #pragma unroll
            for (int v = 0; v < TEAMS; ++v) { shs += sacc[0][v][0]; trs += sacc[0][v][1]; }
            const float l2tot  = atomicAdd(l2acc, 0.0f);  // coherent read
            const float l2     = l2tot / (float)(3 * NPIX);
            const float sharp  = (shs / (float)NS) * 0.001f;
            const float transp = -(trs / (float)NS) * 0.001f;
            const float psnr   = 10.0f * log10f(1.0f / (l2 + 1e-12f));
            out[3 * NPIX] = l2 + transp + sharp - psnr / 30.0f;
        }
    }
}

// ---------------------------------------------------------------------------
extern "C" void kernel_launch(void* const* d_in, const int* in_sizes, int n_in,
                              void* d_out, int out_size, void* d_ws, size_t ws_size,
                              hipStream_t stream)
{
    const float* canvas = (const float*)d_in[0];
    const float* target = (const float*)d_in[1];
    const float* offset = (const float*)d_in[2];
    const float* sigma  = (const float*)d_in[3];
    const float* theta  = (const float*)d_in[4];
    const float* color  = (const float*)d_in[5];
    const float* alpha  = (const float*)d_in[6];
    float* out = (float*)d_out;
    float* wsf = (float*)d_ws;

    k1_prep<<<NS, 256, 0, stream>>>(offset, sigma, theta, color, alpha, wsf);
    k2_paint<<<K2_GRID, BLK, 0, stream>>>(canvas, target, wsf, out,
                                          wsf + L2_SLOT, (int*)wsf + CNT_SLOT);
}

// Round 9
// 84.642 us; speedup vs baseline: 1.0224x; 1.0224x over previous
//
#include <hip/hip_runtime.h>
#include <hip/hip_bf16.h>

#define HH 256
#define WW 256
#define NPIX (HH*WW)
#define NS 512

#define TEAMS 8                     // waves per k2 block
#define SPT   (NS/TEAMS)            // 64 strokes per wave, one per lane
#define BLK   512
#define K2_GRID 256                 // one block per image row

#define L2E  1.4426950408889634f    // log2(e)
#define XMAX (255.0f/256.0f)

#if __has_builtin(__builtin_amdgcn_exp2f)
#define EXP2F(x) __builtin_amdgcn_exp2f(x)
#else
#define EXP2F(x) exp2f(x)
#endif
#if __has_builtin(__builtin_amdgcn_rcpf)
#define RCPF(x) __builtin_amdgcn_rcpf(x)
#else
#define RCPF(x) (1.0f/(x))
#endif

__device__ __forceinline__ float rlane(float v, int l) {
#if __has_builtin(__builtin_amdgcn_readlane)
    return __int_as_float(__builtin_amdgcn_readlane(__float_as_int(v), l));
#else
    return __shfl(v, l, 64);
#endif
}

// ---------------------------------------------------------------------------
// k0: zero the two cross-block slots (ws is poisoned 0xAA every iteration).
// ---------------------------------------------------------------------------
__global__ __launch_bounds__(64) void k0_init(float* __restrict__ wsf)
{
    if (threadIdx.x == 0) { wsf[0] = 0.0f; ((int*)wsf)[1] = 0; }
}

// ---------------------------------------------------------------------------
// k2 (merged): 256 blocks (one row) x 512 threads (8 waves). Thread tid preps
// stroke tid ENTIRELY in registers: rotation/sigma fold (log2e-scaled),
// per-stroke max via closed-form box-constrained QP (q is jointly convex:
// center + 4 edge argmins, then exact re-eval on a 3x3 grid-snap; error in
// qmin <= ~3e-4, far under tolerance). Row terms folded for this block's y.
// Hot loop per wave: 64 strokes via readlane broadcast; per stroke only
// 2 exps (G0, D0) + Gaussian recurrence G*=D, D*=E for the 4 pixels
// (stride-64). LDS cross-team reduce, fused sigmoid epilogue + l2 partial,
// last block (atomic counter) finalizes the scalar loss from registers.
// ---------------------------------------------------------------------------
__global__ __launch_bounds__(512) void k2_paint(
    const float* __restrict__ canvas, const float* __restrict__ target,
    const float* __restrict__ offset, const float* __restrict__ sigma,
    const float* __restrict__ theta,  const float* __restrict__ color,
    const float* __restrict__ alpha,  float* __restrict__ out,
    float* __restrict__ l2acc,        int* __restrict__ cnt)
{
    const int tid = threadIdx.x;
    const int t   = tid & 63;           // lane
    const int w   = tid >> 6;           // wave id 0..7
    const int row = blockIdx.x;
    const float y = (float)row * (1.0f / 256.0f);

    // ================= per-stroke prep (stroke m = tid) =================
    const int m = tid;
    const float ox = offset[2*m], oy = offset[2*m+1];
    const float s0 = sigma[2*m],  s1 = sigma[2*m+1];
    const float th = theta[m];
    const float al = alpha[m];

    const float kk = 0.84932180028802f;          // sqrt(0.5*log2(e))
    const float ra = kk / s0;                    // ratio = W/H = 1
    const float rb = kk / s1;
    float sn, cs;
    __sincosf(th, &sn, &cs);
    // u = ra[c(x-ox) - s(y-oy)], v = rb[s(x-ox) - c(y-oy)]
    const float P = ra * cs,  Q = -ra * sn,  T1 = ra * (-cs * ox + sn * oy);
    const float R = rb * sn,  S = -rb * cs,  T2 = rb * (-sn * ox + cs * oy);

    // ---- box-QP: min of q=(Px+Qy+T1)^2+(Rx+Sy+T2)^2 over [0,XMAX]^2 ----
    const float den_x = P*P + R*R;               // >= ~1.47
    const float den_y = Q*Q + S*S;               // >= ~1.47
    float bx = 0.0f, by = 0.0f, qb = 3.0e38f;
    {
        // center (skip when reflection is near-singular; then edges capture it)
        const float det = P*S - Q*R;
        if (fabsf(det) > 1e-5f) {
            const float xc = (Q*T2 - S*T1) / det;
            const float yc = (R*T1 - P*T2) / det;
            if (xc >= 0.0f && xc <= XMAX && yc >= 0.0f && yc <= XMAX) {
                const float u = fmaf(P, xc, fmaf(Q, yc, T1));
                const float v = fmaf(R, xc, fmaf(S, yc, T2));
                const float qq = u*u + v*v;
                if (qq < qb) { qb = qq; bx = xc; by = yc; }
            }
        }
        #pragma unroll
        for (int e = 0; e < 2; ++e) {            // edges x = 0, XMAX
            const float X = e ? XMAX : 0.0f;
            const float be = fmaf(P, X, T1), de = fmaf(R, X, T2);
            float ye = -(Q*be + S*de) / den_y;
            ye = fminf(fmaxf(ye, 0.0f), XMAX);
            const float u = fmaf(Q, ye, be), v = fmaf(S, ye, de);
            const float qq = u*u + v*v;
            if (qq < qb) { qb = qq; bx = X; by = ye; }
        }
        #pragma unroll
        for (int e = 0; e < 2; ++e) {            // edges y = 0, XMAX
            const float Y = e ? XMAX : 0.0f;
            const float ae = fmaf(Q, Y, T1), ge = fmaf(S, Y, T2);
            float xe = -(P*ae + R*ge) / den_x;
            xe = fminf(fmaxf(xe, 0.0f), XMAX);
            const float u = fmaf(P, xe, ae), v = fmaf(R, xe, ge);
            const float qq = u*u + v*v;
            if (qq < qb) { qb = qq; bx = xe; by = Y; }
        }
    }
    // exact re-eval on 3x3 grid snap around (bx,by)
    float qmin = 3.0e38f;
    {
        const int jr = (int)floorf(fmaf(bx, 256.0f, 0.5f));
        const int ir = (int)floorf(fmaf(by, 256.0f, 0.5f));
        #pragma unroll
        for (int di = -1; di <= 1; ++di) {
            const int ii = min(255, max(0, ir + di));
            const float yg = (float)ii * (1.0f / 256.0f);
            const float bg = fmaf(Q, yg, T1), dg = fmaf(S, yg, T2);
            #pragma unroll
            for (int dj = -1; dj <= 1; ++dj) {
                const int jj = min(255, max(0, jr + dj));
                const float xg = (float)jj * (1.0f / 256.0f);
                const float u = fmaf(P, xg, bg), v = fmaf(R, xg, dg);
                qmin = fminf(qmin, u*u + v*v);
            }
        }
    }
    const float maxpdf = EXP2F(-qmin);
    const float base   = al / (maxpdf + 1e-6f);
    const float rk0 = base * color[3*m];
    const float rk1 = base * color[3*m+1];
    const float rk2 = base * color[3*m+2];
    const float shv = fabsf(1.0f - s0 / s1);     // sharpness term (this stroke)
    const float trv = fabsf(al);                 // transparency term

    // ---- fold this block's row: g(x) = na2 x^2 + na1 x + na0 = -q(x,y) ----
    const float by_ = fmaf(Q, y, T1);
    const float dy_ = fmaf(S, y, T2);
    const float na2 = -den_x;
    const float na1 = -2.0f * (P * by_ + R * dy_);
    const float na0 = -(by_ * by_ + dy_ * dy_);
    const float rtd = 0.5f * na2;                       // d0 = rtd*x0 + rcd
    const float rcd = fmaf(na2, 0.0625f, 0.25f * na1);  // h = 1/4 (64 px)
    const float rEf = EXP2F(0.125f * na2);              // D ratio = 2^(2*na2*h^2)

    // ================= hot loop: 64 strokes via readlane =================
    const float x0 = (float)t * (1.0f / 256.0f);
    float a00=0,a01=0,a02=0, a10=0,a11=0,a12=0, a20=0,a21=0,a22=0, a30=0,a31=0,a32=0;

    #pragma unroll
    for (int n = 0; n < SPT; ++n) {
        const float c2 = rlane(na2, n);
        const float c1 = rlane(na1, n);
        const float c0 = rlane(na0, n);
        const float td = rlane(rtd, n);
        const float cd = rlane(rcd, n);
        const float Ef = rlane(rEf, n);
        const float k0 = rlane(rk0, n);
        const float k1 = rlane(rk1, n);
        const float k2 = rlane(rk2, n);
        const float g0 = fmaf(fmaf(c2, x0, c1), x0, c0);
        const float d0 = fminf(fmaf(td, x0, cd), 120.0f);  // no 0*inf
        float G = EXP2F(g0);
        float D = EXP2F(d0);
        a00 = fmaf(G, k0, a00); a01 = fmaf(G, k1, a01); a02 = fmaf(G, k2, a02);
        G *= D; D *= Ef;
        a10 = fmaf(G, k0, a10); a11 = fmaf(G, k1, a11); a12 = fmaf(G, k2, a12);
        G *= D; D *= Ef;
        a20 = fmaf(G, k0, a20); a21 = fmaf(G, k1, a21); a22 = fmaf(G, k2, a22);
        G *= D;
        a30 = fmaf(G, k0, a30); a31 = fmaf(G, k1, a31); a32 = fmaf(G, k2, a32);
    }

    // ---- cross-team reduce in LDS ([team][px][ch], stride-3 layout) ----
    __shared__ float sacc[TEAMS][WW][3];     // 24 KB
    sacc[w][t      ][0] = a00; sacc[w][t      ][1] = a01; sacc[w][t      ][2] = a02;
    sacc[w][t +  64][0] = a10; sacc[w][t +  64][1] = a11; sacc[w][t +  64][2] = a12;
    sacc[w][t + 128][0] = a20; sacc[w][t + 128][1] = a21; sacc[w][t + 128][2] = a22;
    sacc[w][t + 192][0] = a30; sacc[w][t + 192][1] = a31; sacc[w][t + 192][2] = a32;
    __syncthreads();

    __shared__ float lw[4];
    __shared__ int sdone;
    if (tid < WW) {
        float z0 = 0.0f, z1 = 0.0f, z2 = 0.0f;
        #pragma unroll
        for (int tm = 0; tm < TEAMS; ++tm) {
            z0 += sacc[tm][tid][0];
            z1 += sacc[tm][tid][1];
            z2 += sacc[tm][tid][2];
        }
        const int p = row * WW + tid;
        z0 += canvas[p];
        z1 += canvas[NPIX + p];
        z2 += canvas[2*NPIX + p];
        const float o0 = RCPF(1.0f + EXP2F(-z0 * L2E));
        const float o1 = RCPF(1.0f + EXP2F(-z1 * L2E));
        const float o2 = RCPF(1.0f + EXP2F(-z2 * L2E));
        out[p]          = o0;
        out[NPIX + p]   = o1;
        out[2*NPIX + p] = o2;
        const float d0 = o0 - target[p];
        const float d1 = o1 - target[NPIX + p];
        const float d2 = o2 - target[2*NPIX + p];
        float l2loc = d0*d0 + d1*d1 + d2*d2;
        #pragma unroll
        for (int off = 32; off > 0; off >>= 1)
            l2loc += __shfl_down(l2loc, off);
        if (t == 0) lw[tid >> 6] = l2loc;
    }
    __syncthreads();

    if (tid == 0) {
        atomicAdd(l2acc, lw[0] + lw[1] + lw[2] + lw[3]);
        __threadfence();
        const int old = atomicAdd(cnt, 1);
        sdone = (old == K2_GRID - 1) ? 1 : 0;
    }
    __syncthreads();

    if (sdone) {  // exactly one block, after all l2 adds are visible
        float sh = shv, tr = trv;                // per-thread stroke terms
        #pragma unroll
        for (int off = 32; off > 0; off >>= 1) {
            sh += __shfl_down(sh, off);
            tr += __shfl_down(tr, off);
        }
        if (t == 0) { sacc[0][w][0] = sh; sacc[0][w][1] = tr; }
        __syncthreads();
        if (tid == 0) {
            float shs = 0.0f, trs = 0.0f;
            #pragma unroll
            for (int v = 0; v < TEAMS; ++v) { shs += sacc[0][v][0]; trs += sacc[0][v][1]; }
            const float l2tot  = atomicAdd(l2acc, 0.0f);  // coherent read
            const float l2     = l2tot / (float)(3 * NPIX);
            const float sharp  = (shs / (float)NS) * 0.001f;
            const float transp = -(trs / (float)NS) * 0.001f;
            const float psnr   = 10.0f * log10f(1.0f / (l2 + 1e-12f));
            out[3 * NPIX] = l2 + transp + sharp - psnr / 30.0f;
        }
    }
}

// ---------------------------------------------------------------------------
extern "C" void kernel_launch(void* const* d_in, const int* in_sizes, int n_in,
                              void* d_out, int out_size, void* d_ws, size_t ws_size,
                              hipStream_t stream)
{
    const float* canvas = (const float*)d_in[0];
    const float* target = (const float*)d_in[1];
    const float* offset = (const float*)d_in[2];
    const float* sigma  = (const float*)d_in[3];
    const float* theta  = (const float*)d_in[4];
    const float* color  = (const float*)d_in[5];
    const float* alpha  = (const float*)d_in[6];
    float* out = (float*)d_out;
    float* wsf = (float*)d_ws;

    k0_init<<<1, 64, 0, stream>>>(wsf);
    k2_paint<<<K2_GRID, BLK, 0, stream>>>(canvas, target, offset, sigma, theta,
                                          color, alpha, out, wsf, (int*)wsf + 1);
}